// Round 4
// baseline (350.620 us; speedup 1.0000x reference)
//
#include <hip/hip_runtime.h>

// Problem constants (fixed by setup_inputs / reference)
#define BN  4       // batch
#define NPT 16384   // points per batch
#define NCC 1024    // FPS centroids (cap on unique orbit length)
#define KNN 32      // neighbors

// KNN select parameters
#define HBINS    2048   // 11-bit level-1 histogram
#define CCH      4      // centroids per chunk-block
#define CAND_CAP 768    // boundary-bin candidate cap (overflow -> exact drill)

// Workspace layout (bytes). Total ~305 KB.
#define OFF_CCOUNT 0                          // BN ints
#define OFF_SCOUNT 64                         // BN ints
#define OFF_SBITS  128                        // BN*(NPT/32) u32 = 8 KB
#define OFF_POOL   (128 + BN*(NPT/32)*4)      // BN*NCC floats = 16 KB
#define ZERO_BYTES (OFF_POOL + BN*NCC*4)
#define OFF_CLIST  ZERO_BYTES                 // BN*NCC ints = 16 KB
#define OFF_H1     (OFF_CLIST + BN*NCC*4)     // BN*512 floats = 8 KB
#define OFF_SLIST  (OFF_H1 + BN*512*4)        // BN*NPT ints = 256 KB

// ---------------------------------------------------------------------------
// FPS v3: 512 threads, 32 pts/thread in regs. Per iteration: wave argmax ->
// packed-u64 LDS atomicMax -> B1 -> owner checks cycle + publishes coords ->
// B2. (2 barriers, no serial scan.) Same arithmetic as proven (absmax 0.0).
// Packed key: (f32 bits of d)<<32 | (NPT-1-idx)  => max = largest d, tie ->
// smallest idx (jnp.argmax semantics). d >= 0 so the float bits are monotone.
// ---------------------------------------------------------------------------
__global__ __launch_bounds__(512) void fps_kernel(const float* __restrict__ x,
    const int* __restrict__ far_init, int* __restrict__ clist, int* __restrict__ ccount)
{
    const int b = blockIdx.x, t = threadIdx.x;
    __shared__ __align__(16) unsigned char seen[NPT];
    __shared__ unsigned long long slot[2];
    __shared__ float cs[3];
    __shared__ int s_done;

    const float* xb = x + (size_t)b * NPT * 3;
    float px[32], py[32], pz[32];
#pragma unroll
    for (int j = 0; j < 32; ++j) {
        int idx = t + (j << 9);
        px[j] = xb[idx*3+0]; py[j] = xb[idx*3+1]; pz[j] = xb[idx*3+2];
    }
    ((uint4*)seen)[t]       = make_uint4(0,0,0,0);
    ((uint4*)seen)[t + 512] = make_uint4(0,0,0,0);
    __syncthreads();
    {
        int f0 = far_init[b];
        if (t == 0) { seen[f0] = 1; s_done = 0; slot[0] = 0ull; slot[1] = 0ull; }
        if (t == (f0 & 511)) {
            int j = f0 >> 9;
            cs[0] = px[j]; cs[1] = py[j]; cs[2] = pz[j];
        }
    }
    __syncthreads();
    float cx = cs[0], cy = cs[1], cz = cs[2];

    for (int it = 0; it < NCC-1; ++it) {
        float best = -1.0f; int bi = 0;
#pragma unroll
        for (int j = 0; j < 32; ++j) {
            float dx = __fsub_rn(px[j], cx);
            float dy = __fsub_rn(py[j], cy);
            float dz = __fsub_rn(pz[j], cz);
            float d  = __fadd_rn(__fadd_rn(__fmul_rn(dx,dx), __fmul_rn(dy,dy)),
                                 __fmul_rn(dz,dz));
            int idx = t + (j << 9);            // ascending: strict > keeps first
            if (d > best) { best = d; bi = idx; }
        }
#pragma unroll
        for (int m = 1; m < 64; m <<= 1) {
            float od = __shfl_xor(best, m, 64);
            int   oi = __shfl_xor(bi,   m, 64);
            if (od > best || (od == best && oi < bi)) { best = od; bi = oi; }
        }
        if ((t & 63) == 0) {
            unsigned long long pk =
                (((unsigned long long)__float_as_uint(best)) << 32)
                | (unsigned)(NPT - 1 - bi);
            atomicMax(&slot[it & 1], pk);
        }
        __syncthreads();                       // B1: slot ready
        int bx = NPT - 1 - (int)(unsigned)(slot[it & 1] & 0xFFFFFFFFull);
        if (t == 0) slot[(it + 1) & 1] = 0ull; // reset next-parity slot
        if (t == (bx & 511)) {
            if (seen[bx]) s_done = 1;          // cycle: centroid SET complete
            else {
                seen[bx] = 1;
                int j = bx >> 9;
                cs[0] = px[j]; cs[1] = py[j]; cs[2] = pz[j];
            }
        }
        __syncthreads();                       // B2: cs / s_done visible
        if (s_done) break;
        cx = cs[0]; cy = cs[1]; cz = cs[2];
    }
    __syncthreads();
    // Emit unique-centroid list (order-free; downstream is set-invariant).
#pragma unroll
    for (int j = 0; j < 32; ++j) {
        int idx = t + (j << 9);
        if (seen[idx]) {
            int pos = atomicAdd(&ccount[b], 1);
            clist[b * NCC + pos] = idx;
        }
    }
}

// ---------------------------------------------------------------------------
// KNN v3: chunk-PARALLEL. grid=(NCC/CCH, BN); each block owns CCH centroids,
// exits early past ccount. Exact 32nd-smallest key per centroid (proven key
// transform), union-mark + compacted list via device-scope bitmask dedupe.
// ---------------------------------------------------------------------------
__device__ __forceinline__ unsigned key_of(float px, float py, float pz, float xn,
                                           float cx, float cy, float cz, float cn)
{
    float dot = __fadd_rn(__fadd_rn(__fmul_rn(cx,px), __fmul_rn(cy,py)), __fmul_rn(cz,pz));
    float d2  = __fsub_rn(__fadd_rn(cn, xn), __fmul_rn(2.0f, dot));
    unsigned u = __float_as_uint(d2);
    return u ^ ((u >> 31) ? 0xFFFFFFFFu : 0x80000000u);
}

// All 64 lanes of ONE wave call this; single lane writes {bin, below} to LDS.
__device__ __forceinline__ void wave_scan_bins(const unsigned* __restrict__ H,
    int nbins, int rem, int lane, int* __restrict__ out_bin, int* __restrict__ out_below)
{
    int per = nbins >> 6;
    int base = lane * per;
    unsigned part = 0;
    for (int q = 0; q < per; ++q) part += H[base + q];
    unsigned inc = part;
#pragma unroll
    for (int m = 1; m < 64; m <<= 1) {
        unsigned u = __shfl_up(inc, m, 64);
        if (lane >= m) inc += u;
    }
    unsigned exc = inc - part;
    unsigned long long mk = __ballot(exc < (unsigned)rem && inc >= (unsigned)rem);
    int src = __ffsll((long long)mk) - 1;
    if (lane == src) {
        unsigned run = exc; int bb = base;
        for (int q = 0; q < per; ++q) {
            unsigned h = H[base + q];
            if (run + h >= (unsigned)rem) { bb = base + q; break; }
            run += h;
        }
        *out_bin = bb; *out_below = (int)run;
    }
}

__global__ __launch_bounds__(1024) void knn_kernel(const float* __restrict__ x,
    const int* __restrict__ clist, const int* __restrict__ ccount,
    unsigned* __restrict__ sbits, int* __restrict__ slist, int* __restrict__ scount)
{
    const int b = blockIdx.y, t = threadIdx.x;
    const int lane = t & 63, w = t >> 6;
    const int cnt = ccount[b];
    const int cbase = blockIdx.x * CCH;
    if (cbase >= cnt) return;                  // uniform exit, before any barrier
    const int nc = min(CCH, cnt - cbase);
    const float* xb = x + (size_t)b * NPT * 3;

    __shared__ unsigned hist[CCH * HBINS];     // 32 KB
    __shared__ unsigned cand[CCH * CAND_CAP];  // 12 KB
    __shared__ float cpx[CCH], cpy[CCH], cpz[CCH], cpn[CCH];
    __shared__ unsigned candCnt[CCH];
    __shared__ int s_bb[CCH], s_below[CCH], s_rrem[CCH], s_need[CCH], s_pref[CCH];
    __shared__ unsigned s_tau[CCH];
    __shared__ int s_tbin, s_tbelow;

    if (t < nc) {
        int ci = clist[b * NCC + cbase + t];
        float cx = xb[ci*3], cy = xb[ci*3+1], cz = xb[ci*3+2];
        cpx[t] = cx; cpy[t] = cy; cpz[t] = cz;
        cpn[t] = __fadd_rn(__fadd_rn(__fmul_rn(cx,cx), __fmul_rn(cy,cy)), __fmul_rn(cz,cz));
        candCnt[t] = 0;
    }
    for (int i = t; i < CCH * HBINS; i += 1024) hist[i] = 0;
    __syncthreads();

    // Sweep 1: level-1 histograms (top 11 bits), all chunk centroids at once.
    for (int j = 0; j < NPT/1024; ++j) {
        int i = t + (j << 10);
        float px = xb[i*3], py = xb[i*3+1], pz = xb[i*3+2];
        float xn = __fadd_rn(__fadd_rn(__fmul_rn(px,px), __fmul_rn(py,py)), __fmul_rn(pz,pz));
#pragma unroll
        for (int c = 0; c < CCH; ++c) {
            if (c < nc) {
                unsigned key = key_of(px,py,pz,xn, cpx[c],cpy[c],cpz[c],cpn[c]);
                atomicAdd(&hist[c*HBINS + (key >> 21)], 1u);
            }
        }
    }
    __syncthreads();

    if (w < nc)
        wave_scan_bins(&hist[w*HBINS], HBINS, KNN, lane, &s_bb[w], &s_below[w]);
    __syncthreads();
    if (t < nc) s_rrem[t] = KNN - s_below[t];
    __syncthreads();

    // Sweep 2: collect candidate keys in each centroid's boundary bin.
    for (int j = 0; j < NPT/1024; ++j) {
        int i = t + (j << 10);
        float px = xb[i*3], py = xb[i*3+1], pz = xb[i*3+2];
        float xn = __fadd_rn(__fadd_rn(__fmul_rn(px,px), __fmul_rn(py,py)), __fmul_rn(pz,pz));
#pragma unroll
        for (int c = 0; c < CCH; ++c) {
            if (c < nc) {
                unsigned key = key_of(px,py,pz,xn, cpx[c],cpy[c],cpz[c],cpn[c]);
                if ((int)(key >> 21) == s_bb[c]) {
                    unsigned pos = atomicAdd(&candCnt[c], 1u);
                    if (pos < CAND_CAP) cand[c*CAND_CAP + pos] = key;
                }
            }
        }
    }
    __syncthreads();

    // Exact tau: rank-select (rrem-th smallest with multiplicity) per wave.
    if (w < nc) {
        unsigned cc = candCnt[w];
        if (cc <= CAND_CAP) {
            int r = s_rrem[w] - 1;
            const unsigned* C = &cand[w*CAND_CAP];
            for (int idx = lane; idx < (int)cc; idx += 64) {
                unsigned k = C[idx]; int rank = 0;
                for (int q = 0; q < (int)cc; ++q) {
                    unsigned kq = C[q];
                    rank += (kq < k || (kq == k && q < idx)) ? 1 : 0;
                }
                if (rank == r) s_tau[w] = k;   // exactly one idx matches
            }
            if (lane == 0) s_need[w] = 0;
        } else if (lane == 0) s_need[w] = 1;
    }
    __syncthreads();

    // Rare exact drill-down for overflowed boundary bins (guaranteed exact).
    for (int c = 0; c < nc; ++c) {
        if (s_need[c]) {                       // uniform (LDS broadcast)
            const float cx = cpx[c], cy = cpy[c], cz = cpz[c], cn = cpn[c];
            // level 2: bits [10,21)
            for (int i = t; i < HBINS; i += 1024) hist[i] = 0;
            __syncthreads();
            for (int j = 0; j < NPT/1024; ++j) {
                int i = t + (j << 10);
                float px = xb[i*3], py = xb[i*3+1], pz = xb[i*3+2];
                float xn = __fadd_rn(__fadd_rn(__fmul_rn(px,px), __fmul_rn(py,py)), __fmul_rn(pz,pz));
                unsigned key = key_of(px,py,pz,xn, cx,cy,cz,cn);
                if ((int)(key >> 21) == s_bb[c]) atomicAdd(&hist[(key >> 10) & 2047u], 1u);
            }
            __syncthreads();
            if (w == 0) wave_scan_bins(hist, HBINS, s_rrem[c], lane, &s_tbin, &s_tbelow);
            __syncthreads();
            if (t == 0) { s_pref[c] = (s_bb[c] << 11) | s_tbin; s_rrem[c] -= s_tbelow; }
            __syncthreads();
            // level 3: bits [0,10) -> bin IS the exact remaining key bits
            for (int i = t; i < 1024; i += 1024) hist[i] = 0;
            __syncthreads();
            for (int j = 0; j < NPT/1024; ++j) {
                int i = t + (j << 10);
                float px = xb[i*3], py = xb[i*3+1], pz = xb[i*3+2];
                float xn = __fadd_rn(__fadd_rn(__fmul_rn(px,px), __fmul_rn(py,py)), __fmul_rn(pz,pz));
                unsigned key = key_of(px,py,pz,xn, cx,cy,cz,cn);
                if ((int)(key >> 10) == s_pref[c]) atomicAdd(&hist[key & 1023u], 1u);
            }
            __syncthreads();
            if (w == 0) wave_scan_bins(hist, 1024, s_rrem[c], lane, &s_tbin, &s_tbelow);
            __syncthreads();
            if (t == 0) s_tau[c] = (((unsigned)s_pref[c]) << 10) | (unsigned)s_tbin;
            __syncthreads();
        }
    }
    __syncthreads();                           // s_tau visible to all

    // Sweep 3: union-mark (key <= tau) + build compacted list (deduped).
    for (int j = 0; j < NPT/1024; ++j) {
        int i = t + (j << 10);
        float px = xb[i*3], py = xb[i*3+1], pz = xb[i*3+2];
        float xn = __fadd_rn(__fadd_rn(__fmul_rn(px,px), __fmul_rn(py,py)), __fmul_rn(pz,pz));
        bool sel = false;
#pragma unroll
        for (int c = 0; c < CCH; ++c) {
            if (c < nc) {
                unsigned key = key_of(px,py,pz,xn, cpx[c],cpy[c],cpz[c],cpn[c]);
                sel |= (key <= s_tau[c]);
            }
        }
        if (sel) {
            unsigned bit = 1u << (i & 31);
            unsigned old = atomicOr(&sbits[b*(NPT/32) + (i >> 5)], bit);
            if (!(old & bit)) {
                int pos = atomicAdd(&scount[b], 1);
                slist[b * NPT + pos] = i;
            }
        }
    }
}

// ---------------------------------------------------------------------------
// MLP v3: one block per 64-pt tile; L1-L4 computed ONCE, L5 all 1024 ocs in
// 4 sequential 256-oc quarters. Fused global max-pool (proven epilogue).
// ---------------------------------------------------------------------------
__device__ __forceinline__ void layer64(const float* __restrict__ src,
    float* __restrict__ dst, const float* __restrict__ w,
    const float* __restrict__ bias, int ocb, int p)
{
    float a0 = bias[ocb+0], a1 = bias[ocb+1], a2 = bias[ocb+2], a3 = bias[ocb+3];
#pragma unroll 8
    for (int k = 0; k < 64; ++k) {
        float a = src[k*64+p];
        a0 += a * w[(ocb+0)*64+k];
        a1 += a * w[(ocb+1)*64+k];
        a2 += a * w[(ocb+2)*64+k];
        a3 += a * w[(ocb+3)*64+k];
    }
    dst[(ocb+0)*64+p] = fmaxf(a0, 0.0f);
    dst[(ocb+1)*64+p] = fmaxf(a1, 0.0f);
    dst[(ocb+2)*64+p] = fmaxf(a2, 0.0f);
    dst[(ocb+3)*64+p] = fmaxf(a3, 0.0f);
}

__global__ __launch_bounds__(1024) void mlp_kernel(const float* __restrict__ x,
    const int* __restrict__ sel_list, const int* __restrict__ sel_count,
    const float* __restrict__ w1, const float* __restrict__ b1,
    const float* __restrict__ w2, const float* __restrict__ b2,
    const float* __restrict__ w3, const float* __restrict__ b3,
    const float* __restrict__ w4, const float* __restrict__ b4,
    const float* __restrict__ w5, const float* __restrict__ b5,
    float* __restrict__ pool)
{
    const int b = blockIdx.y, t = threadIdx.x;
    const int cnt = sel_count[b];
    const int p = t & 63;
    const int wv = __builtin_amdgcn_readfirstlane(t >> 6);  // 0..15, wave-uniform

    __shared__ float A[128 * 64];   // 32 KB
    __shared__ float Bf[64 * 64];   // 16 KB

    for (int base = blockIdx.x << 6; base < cnt; base += (128 << 6)) {
        const int npts = min(64, cnt - base);
        __syncthreads();                        // previous tile's reads done
        if (t < 64) {
            int idx = sel_list[b * NPT + base + min(t, npts - 1)];  // pad = dup last
            const float* xp = x + ((size_t)b * NPT + idx) * 3;
            A[t] = xp[0]; A[64 + t] = xp[1]; A[128 + t] = xp[2];
        }
        __syncthreads();
        {   // L1: 3->64
            float a0 = A[p], a1 = A[64 + p], a2 = A[128 + p];
            int ocb = wv * 4;
#pragma unroll
            for (int i = 0; i < 4; ++i) {
                int oc = ocb + i;
                float acc = b1[oc] + a0 * w1[oc*3+0] + a1 * w1[oc*3+1] + a2 * w1[oc*3+2];
                Bf[oc*64+p] = fmaxf(acc, 0.0f);
            }
        }
        __syncthreads();
        layer64(Bf, A, w2, b2, wv * 4, p);      // L2: 64->64
        __syncthreads();
        layer64(A, Bf, w3, b3, wv * 4, p);      // L3: 64->64
        __syncthreads();
        {   // L4: 64->128
            int ocb = wv * 8;
            float acc[8];
#pragma unroll
            for (int i = 0; i < 8; ++i) acc[i] = b4[ocb + i];
#pragma unroll 4
            for (int k = 0; k < 64; ++k) {
                float a = Bf[k*64+p];
#pragma unroll
                for (int i = 0; i < 8; ++i) acc[i] += a * w4[(ocb+i)*64+k];
            }
#pragma unroll
            for (int i = 0; i < 8; ++i) A[(ocb+i)*64+p] = fmaxf(acc[i], 0.0f);
        }
        __syncthreads();
        // L5 + max-pool: all 1024 ocs, 4 quarters of 256 (16/wave each).
        for (int zz = 0; zz < 4; ++zz) {
            int ocb = zz * 256 + wv * 16;
            float acc[16];
#pragma unroll
            for (int i = 0; i < 16; ++i) acc[i] = b5[ocb + i];
#pragma unroll 4
            for (int k = 0; k < 128; ++k) {
                float a = A[k*64+p];
#pragma unroll
                for (int i = 0; i < 16; ++i) acc[i] += a * w5[(ocb+i)*128+k];
            }
#pragma unroll
            for (int i = 0; i < 16; ++i) {
                float v = (p < npts) ? fmaxf(acc[i], 0.0f) : 0.0f;  // pad -> 0 (relu>=0)
#pragma unroll
                for (int m = 1; m < 64; m <<= 1) v = fmaxf(v, __shfl_xor(v, m, 64));
                if (p == 0) atomicMax((int*)&pool[b*NCC + ocb + i], __float_as_int(v));
            }
        }
    }
}

// ---------------------------------------------------------------------------
// FC head (proven). head1: FC1 (1024->512 relu), 4 blocks/batch.
// ---------------------------------------------------------------------------
__global__ __launch_bounds__(1024) void head1_kernel(const float* __restrict__ pool,
    const float* __restrict__ fw1, const float* __restrict__ fb1,
    float* __restrict__ h1g)
{
    const int bo = blockIdx.x, b = blockIdx.y, t = threadIdx.x;
    const int lane = t & 63, w = t >> 6;
    __shared__ float g[1024];
    g[t] = pool[b*NCC + t];
    __syncthreads();
    int o = bo * 128 + w * 8;
#pragma unroll
    for (int i = 0; i < 8; ++i, ++o) {
        float acc = 0.0f;
#pragma unroll
        for (int j = 0; j < 16; ++j) {
            int k = lane + (j << 6);
            acc += g[k] * fw1[o*1024 + k];
        }
#pragma unroll
        for (int m = 1; m < 64; m <<= 1) acc += __shfl_xor(acc, m, 64);
        if (lane == 0) h1g[b*512 + o] = fmaxf(acc + fb1[o], 0.0f);
    }
}

// head2: FC2 (512->256 relu) + FC3 (256->3). One block per batch.
__global__ __launch_bounds__(1024) void head2_kernel(const float* __restrict__ h1g,
    const float* __restrict__ fw2, const float* __restrict__ fb2,
    const float* __restrict__ fw3, const float* __restrict__ fb3,
    float* __restrict__ out)
{
    const int b = blockIdx.x, t = threadIdx.x;
    const int lane = t & 63, w = t >> 6;
    __shared__ float h1[512], h2[256];
    if (t < 512) h1[t] = h1g[b*512 + t];
    __syncthreads();
#pragma unroll
    for (int i = 0; i < 16; ++i) {
        int o = w * 16 + i;
        float acc = 0.0f;
#pragma unroll
        for (int j = 0; j < 8; ++j) {
            int k = lane + (j << 6);
            acc += h1[k] * fw2[o*512 + k];
        }
#pragma unroll
        for (int m = 1; m < 64; m <<= 1) acc += __shfl_xor(acc, m, 64);
        if (lane == 0) h2[o] = fmaxf(acc + fb2[o], 0.0f);
    }
    __syncthreads();
    if (w < 3) {
        float acc = 0.0f;
#pragma unroll
        for (int j = 0; j < 4; ++j) {
            int k = lane + (j << 6);
            acc += h2[k] * fw3[w*256 + k];
        }
#pragma unroll
        for (int m = 1; m < 64; m <<= 1) acc += __shfl_xor(acc, m, 64);
        if (lane == 0) out[b*3 + w] = acc + fb3[w];
    }
}

extern "C" void kernel_launch(void* const* d_in, const int* in_sizes, int n_in,
                              void* d_out, int out_size, void* d_ws, size_t ws_size,
                              hipStream_t stream)
{
    const float* x    = (const float*)d_in[0];
    const int*   far0 = (const int*)  d_in[1];
    const float *w1 = (const float*)d_in[2],  *b1 = (const float*)d_in[3];
    const float *w2 = (const float*)d_in[4],  *b2 = (const float*)d_in[5];
    const float *w3 = (const float*)d_in[6],  *b3 = (const float*)d_in[7];
    const float *w4 = (const float*)d_in[8],  *b4 = (const float*)d_in[9];
    const float *w5 = (const float*)d_in[10], *b5 = (const float*)d_in[11];
    const float *fw1 = (const float*)d_in[12], *fb1 = (const float*)d_in[13];
    const float *fw2 = (const float*)d_in[14], *fb2 = (const float*)d_in[15];
    const float *fw3 = (const float*)d_in[16], *fb3 = (const float*)d_in[17];

    char* ws = (char*)d_ws;
    int*      ccount = (int*)     (ws + OFF_CCOUNT);
    int*      scount = (int*)     (ws + OFF_SCOUNT);
    unsigned* sbits  = (unsigned*)(ws + OFF_SBITS);
    float*    pool   = (float*)   (ws + OFF_POOL);
    int*      clist  = (int*)     (ws + OFF_CLIST);
    float*    h1g    = (float*)   (ws + OFF_H1);
    int*      slist  = (int*)     (ws + OFF_SLIST);

    hipMemsetAsync(d_ws, 0, ZERO_BYTES, stream);  // counts, sbits, pool -> 0

    fps_kernel<<<BN, 512, 0, stream>>>(x, far0, clist, ccount);
    knn_kernel<<<dim3(NCC/CCH, BN), 1024, 0, stream>>>(x, clist, ccount, sbits, slist, scount);
    mlp_kernel<<<dim3(128, BN), 1024, 0, stream>>>(x, slist, scount,
        w1,b1, w2,b2, w3,b3, w4,b4, w5,b5, pool);
    head1_kernel<<<dim3(4, BN), 1024, 0, stream>>>(pool, fw1, fb1, h1g);
    head2_kernel<<<BN, 1024, 0, stream>>>(h1g, fw2,fb2, fw3,fb3, (float*)d_out);
}

// Round 5
// 260.852 us; speedup vs baseline: 1.3441x; 1.3441x over previous
//
#include <hip/hip_runtime.h>

// Problem constants (fixed by setup_inputs / reference)
#define BN  4       // batch
#define NPT 16384   // points per batch
#define NCC 1024    // FPS centroids (cap on unique orbit length)
#define KNN 32      // neighbors

// KNN select parameters
#define HBINS    2048   // 11-bit level-1 histogram
#define CCH      4      // centroids per chunk-block
#define CAND_CAP 768    // boundary-bin candidate cap (overflow -> exact drill)

// Workspace layout (bytes). Total ~305 KB.
#define OFF_CCOUNT 0                          // BN ints
#define OFF_SCOUNT 64                         // BN ints
#define OFF_SBITS  128                        // BN*(NPT/32) u32 = 8 KB
#define OFF_POOL   (128 + BN*(NPT/32)*4)      // BN*NCC floats = 16 KB
#define ZERO_BYTES (OFF_POOL + BN*NCC*4)
#define OFF_CLIST  ZERO_BYTES                 // BN*NCC ints = 16 KB
#define OFF_H1     (OFF_CLIST + BN*NCC*4)     // BN*512 floats = 8 KB
#define OFF_SLIST  (OFF_H1 + BN*512*4)        // BN*NPT ints = 256 KB

// ---------------------------------------------------------------------------
// FPS v3 (proven R4): 512 threads, 32 pts/thread in regs, packed-u64 argmax,
// 2 barriers/iter, cycle detection. absmax 0.0.
// ---------------------------------------------------------------------------
__global__ __launch_bounds__(512) void fps_kernel(const float* __restrict__ x,
    const int* __restrict__ far_init, int* __restrict__ clist, int* __restrict__ ccount)
{
    const int b = blockIdx.x, t = threadIdx.x;
    __shared__ __align__(16) unsigned char seen[NPT];
    __shared__ unsigned long long slot[2];
    __shared__ float cs[3];
    __shared__ int s_done;

    const float* xb = x + (size_t)b * NPT * 3;
    float px[32], py[32], pz[32];
#pragma unroll
    for (int j = 0; j < 32; ++j) {
        int idx = t + (j << 9);
        px[j] = xb[idx*3+0]; py[j] = xb[idx*3+1]; pz[j] = xb[idx*3+2];
    }
    ((uint4*)seen)[t]       = make_uint4(0,0,0,0);
    ((uint4*)seen)[t + 512] = make_uint4(0,0,0,0);
    __syncthreads();
    {
        int f0 = far_init[b];
        if (t == 0) { seen[f0] = 1; s_done = 0; slot[0] = 0ull; slot[1] = 0ull; }
        if (t == (f0 & 511)) {
            int j = f0 >> 9;
            cs[0] = px[j]; cs[1] = py[j]; cs[2] = pz[j];
        }
    }
    __syncthreads();
    float cx = cs[0], cy = cs[1], cz = cs[2];

    for (int it = 0; it < NCC-1; ++it) {
        float best = -1.0f; int bi = 0;
#pragma unroll
        for (int j = 0; j < 32; ++j) {
            float dx = __fsub_rn(px[j], cx);
            float dy = __fsub_rn(py[j], cy);
            float dz = __fsub_rn(pz[j], cz);
            float d  = __fadd_rn(__fadd_rn(__fmul_rn(dx,dx), __fmul_rn(dy,dy)),
                                 __fmul_rn(dz,dz));
            int idx = t + (j << 9);            // ascending: strict > keeps first
            if (d > best) { best = d; bi = idx; }
        }
#pragma unroll
        for (int m = 1; m < 64; m <<= 1) {
            float od = __shfl_xor(best, m, 64);
            int   oi = __shfl_xor(bi,   m, 64);
            if (od > best || (od == best && oi < bi)) { best = od; bi = oi; }
        }
        if ((t & 63) == 0) {
            unsigned long long pk =
                (((unsigned long long)__float_as_uint(best)) << 32)
                | (unsigned)(NPT - 1 - bi);
            atomicMax(&slot[it & 1], pk);
        }
        __syncthreads();                       // B1: slot ready
        int bx = NPT - 1 - (int)(unsigned)(slot[it & 1] & 0xFFFFFFFFull);
        if (t == 0) slot[(it + 1) & 1] = 0ull; // reset next-parity slot
        if (t == (bx & 511)) {
            if (seen[bx]) s_done = 1;          // cycle: centroid SET complete
            else {
                seen[bx] = 1;
                int j = bx >> 9;
                cs[0] = px[j]; cs[1] = py[j]; cs[2] = pz[j];
            }
        }
        __syncthreads();                       // B2: cs / s_done visible
        if (s_done) break;
        cx = cs[0]; cy = cs[1]; cz = cs[2];
    }
    __syncthreads();
    // Emit unique-centroid list (order-free; downstream is set-invariant).
#pragma unroll
    for (int j = 0; j < 32; ++j) {
        int idx = t + (j << 9);
        if (seen[idx]) {
            int pos = atomicAdd(&ccount[b], 1);
            clist[b * NCC + pos] = idx;
        }
    }
}

// ---------------------------------------------------------------------------
// KNN v3 (proven R4): chunk-PARALLEL, grid=(NCC/CCH, BN). Exact 32nd-smallest
// key per centroid, union-mark + compacted list via bitmask dedupe.
// ---------------------------------------------------------------------------
__device__ __forceinline__ unsigned key_of(float px, float py, float pz, float xn,
                                           float cx, float cy, float cz, float cn)
{
    float dot = __fadd_rn(__fadd_rn(__fmul_rn(cx,px), __fmul_rn(cy,py)), __fmul_rn(cz,pz));
    float d2  = __fsub_rn(__fadd_rn(cn, xn), __fmul_rn(2.0f, dot));
    unsigned u = __float_as_uint(d2);
    return u ^ ((u >> 31) ? 0xFFFFFFFFu : 0x80000000u);
}

__device__ __forceinline__ void wave_scan_bins(const unsigned* __restrict__ H,
    int nbins, int rem, int lane, int* __restrict__ out_bin, int* __restrict__ out_below)
{
    int per = nbins >> 6;
    int base = lane * per;
    unsigned part = 0;
    for (int q = 0; q < per; ++q) part += H[base + q];
    unsigned inc = part;
#pragma unroll
    for (int m = 1; m < 64; m <<= 1) {
        unsigned u = __shfl_up(inc, m, 64);
        if (lane >= m) inc += u;
    }
    unsigned exc = inc - part;
    unsigned long long mk = __ballot(exc < (unsigned)rem && inc >= (unsigned)rem);
    int src = __ffsll((long long)mk) - 1;
    if (lane == src) {
        unsigned run = exc; int bb = base;
        for (int q = 0; q < per; ++q) {
            unsigned h = H[base + q];
            if (run + h >= (unsigned)rem) { bb = base + q; break; }
            run += h;
        }
        *out_bin = bb; *out_below = (int)run;
    }
}

__global__ __launch_bounds__(1024) void knn_kernel(const float* __restrict__ x,
    const int* __restrict__ clist, const int* __restrict__ ccount,
    unsigned* __restrict__ sbits, int* __restrict__ slist, int* __restrict__ scount)
{
    const int b = blockIdx.y, t = threadIdx.x;
    const int lane = t & 63, w = t >> 6;
    const int cnt = ccount[b];
    const int cbase = blockIdx.x * CCH;
    if (cbase >= cnt) return;                  // uniform exit, before any barrier
    const int nc = min(CCH, cnt - cbase);
    const float* xb = x + (size_t)b * NPT * 3;

    __shared__ unsigned hist[CCH * HBINS];     // 32 KB
    __shared__ unsigned cand[CCH * CAND_CAP];  // 12 KB
    __shared__ float cpx[CCH], cpy[CCH], cpz[CCH], cpn[CCH];
    __shared__ unsigned candCnt[CCH];
    __shared__ int s_bb[CCH], s_below[CCH], s_rrem[CCH], s_need[CCH], s_pref[CCH];
    __shared__ unsigned s_tau[CCH];
    __shared__ int s_tbin, s_tbelow;

    if (t < nc) {
        int ci = clist[b * NCC + cbase + t];
        float cx = xb[ci*3], cy = xb[ci*3+1], cz = xb[ci*3+2];
        cpx[t] = cx; cpy[t] = cy; cpz[t] = cz;
        cpn[t] = __fadd_rn(__fadd_rn(__fmul_rn(cx,cx), __fmul_rn(cy,cy)), __fmul_rn(cz,cz));
        candCnt[t] = 0;
    }
    for (int i = t; i < CCH * HBINS; i += 1024) hist[i] = 0;
    __syncthreads();

    // Sweep 1: level-1 histograms (top 11 bits), all chunk centroids at once.
    for (int j = 0; j < NPT/1024; ++j) {
        int i = t + (j << 10);
        float px = xb[i*3], py = xb[i*3+1], pz = xb[i*3+2];
        float xn = __fadd_rn(__fadd_rn(__fmul_rn(px,px), __fmul_rn(py,py)), __fmul_rn(pz,pz));
#pragma unroll
        for (int c = 0; c < CCH; ++c) {
            if (c < nc) {
                unsigned key = key_of(px,py,pz,xn, cpx[c],cpy[c],cpz[c],cpn[c]);
                atomicAdd(&hist[c*HBINS + (key >> 21)], 1u);
            }
        }
    }
    __syncthreads();

    if (w < nc)
        wave_scan_bins(&hist[w*HBINS], HBINS, KNN, lane, &s_bb[w], &s_below[w]);
    __syncthreads();
    if (t < nc) s_rrem[t] = KNN - s_below[t];
    __syncthreads();

    // Sweep 2: collect candidate keys in each centroid's boundary bin.
    for (int j = 0; j < NPT/1024; ++j) {
        int i = t + (j << 10);
        float px = xb[i*3], py = xb[i*3+1], pz = xb[i*3+2];
        float xn = __fadd_rn(__fadd_rn(__fmul_rn(px,px), __fmul_rn(py,py)), __fmul_rn(pz,pz));
#pragma unroll
        for (int c = 0; c < CCH; ++c) {
            if (c < nc) {
                unsigned key = key_of(px,py,pz,xn, cpx[c],cpy[c],cpz[c],cpn[c]);
                if ((int)(key >> 21) == s_bb[c]) {
                    unsigned pos = atomicAdd(&candCnt[c], 1u);
                    if (pos < CAND_CAP) cand[c*CAND_CAP + pos] = key;
                }
            }
        }
    }
    __syncthreads();

    // Exact tau: rank-select (rrem-th smallest with multiplicity) per wave.
    if (w < nc) {
        unsigned cc = candCnt[w];
        if (cc <= CAND_CAP) {
            int r = s_rrem[w] - 1;
            const unsigned* C = &cand[w*CAND_CAP];
            for (int idx = lane; idx < (int)cc; idx += 64) {
                unsigned k = C[idx]; int rank = 0;
                for (int q = 0; q < (int)cc; ++q) {
                    unsigned kq = C[q];
                    rank += (kq < k || (kq == k && q < idx)) ? 1 : 0;
                }
                if (rank == r) s_tau[w] = k;   // exactly one idx matches
            }
            if (lane == 0) s_need[w] = 0;
        } else if (lane == 0) s_need[w] = 1;
    }
    __syncthreads();

    // Rare exact drill-down for overflowed boundary bins (guaranteed exact).
    for (int c = 0; c < nc; ++c) {
        if (s_need[c]) {                       // uniform (LDS broadcast)
            const float cx = cpx[c], cy = cpy[c], cz = cpz[c], cn = cpn[c];
            // level 2: bits [10,21)
            for (int i = t; i < HBINS; i += 1024) hist[i] = 0;
            __syncthreads();
            for (int j = 0; j < NPT/1024; ++j) {
                int i = t + (j << 10);
                float px = xb[i*3], py = xb[i*3+1], pz = xb[i*3+2];
                float xn = __fadd_rn(__fadd_rn(__fmul_rn(px,px), __fmul_rn(py,py)), __fmul_rn(pz,pz));
                unsigned key = key_of(px,py,pz,xn, cx,cy,cz,cn);
                if ((int)(key >> 21) == s_bb[c]) atomicAdd(&hist[(key >> 10) & 2047u], 1u);
            }
            __syncthreads();
            if (w == 0) wave_scan_bins(hist, HBINS, s_rrem[c], lane, &s_tbin, &s_tbelow);
            __syncthreads();
            if (t == 0) { s_pref[c] = (s_bb[c] << 11) | s_tbin; s_rrem[c] -= s_tbelow; }
            __syncthreads();
            // level 3: bits [0,10) -> bin IS the exact remaining key bits
            for (int i = t; i < 1024; i += 1024) hist[i] = 0;
            __syncthreads();
            for (int j = 0; j < NPT/1024; ++j) {
                int i = t + (j << 10);
                float px = xb[i*3], py = xb[i*3+1], pz = xb[i*3+2];
                float xn = __fadd_rn(__fadd_rn(__fmul_rn(px,px), __fmul_rn(py,py)), __fmul_rn(pz,pz));
                unsigned key = key_of(px,py,pz,xn, cx,cy,cz,cn);
                if ((int)(key >> 10) == s_pref[c]) atomicAdd(&hist[key & 1023u], 1u);
            }
            __syncthreads();
            if (w == 0) wave_scan_bins(hist, 1024, s_rrem[c], lane, &s_tbin, &s_tbelow);
            __syncthreads();
            if (t == 0) s_tau[c] = (((unsigned)s_pref[c]) << 10) | (unsigned)s_tbin;
            __syncthreads();
        }
    }
    __syncthreads();                           // s_tau visible to all

    // Sweep 3: union-mark (key <= tau) + build compacted list (deduped).
    for (int j = 0; j < NPT/1024; ++j) {
        int i = t + (j << 10);
        float px = xb[i*3], py = xb[i*3+1], pz = xb[i*3+2];
        float xn = __fadd_rn(__fadd_rn(__fmul_rn(px,px), __fmul_rn(py,py)), __fmul_rn(pz,pz));
        bool sel = false;
#pragma unroll
        for (int c = 0; c < CCH; ++c) {
            if (c < nc) {
                unsigned key = key_of(px,py,pz,xn, cpx[c],cpy[c],cpz[c],cpn[c]);
                sel |= (key <= s_tau[c]);
            }
        }
        if (sel) {
            unsigned bit = 1u << (i & 31);
            unsigned old = atomicOr(&sbits[b*(NPT/32) + (i >> 5)], bit);
            if (!(old & bit)) {
                int pos = atomicAdd(&scount[b], 1);
                slist[b * NPT + pos] = i;
            }
        }
    }
}

// ---------------------------------------------------------------------------
// MLP: REVERTED to proven R3 shape (z-split quarter per block, 56 us) with
// grid-x 16 -> 64 so each block handles ~1 tile (shorter serial chain).
// R4's serial-quarters variant regressed 56 -> 197 us (4x weight footprint
// per block); do not reintroduce.
// ---------------------------------------------------------------------------
__device__ __forceinline__ void layer64(const float* __restrict__ src,
    float* __restrict__ dst, const float* __restrict__ w,
    const float* __restrict__ bias, int ocb, int p)
{
    float a0 = bias[ocb+0], a1 = bias[ocb+1], a2 = bias[ocb+2], a3 = bias[ocb+3];
#pragma unroll 8
    for (int k = 0; k < 64; ++k) {
        float a = src[k*64+p];
        a0 += a * w[(ocb+0)*64+k];
        a1 += a * w[(ocb+1)*64+k];
        a2 += a * w[(ocb+2)*64+k];
        a3 += a * w[(ocb+3)*64+k];
    }
    dst[(ocb+0)*64+p] = fmaxf(a0, 0.0f);
    dst[(ocb+1)*64+p] = fmaxf(a1, 0.0f);
    dst[(ocb+2)*64+p] = fmaxf(a2, 0.0f);
    dst[(ocb+3)*64+p] = fmaxf(a3, 0.0f);
}

__global__ __launch_bounds__(1024) void mlp_kernel(const float* __restrict__ x,
    const int* __restrict__ sel_list, const int* __restrict__ sel_count,
    const float* __restrict__ w1, const float* __restrict__ b1,
    const float* __restrict__ w2, const float* __restrict__ b2,
    const float* __restrict__ w3, const float* __restrict__ b3,
    const float* __restrict__ w4, const float* __restrict__ b4,
    const float* __restrict__ w5, const float* __restrict__ b5,
    float* __restrict__ pool)
{
    const int b = blockIdx.y, z = blockIdx.z, t = threadIdx.x;
    const int cnt = sel_count[b];
    const int p = t & 63;
    const int wv = __builtin_amdgcn_readfirstlane(t >> 6);  // 0..15, wave-uniform

    __shared__ float A[128 * 64];   // 32 KB
    __shared__ float Bf[64 * 64];   // 16 KB

    for (int base = blockIdx.x << 6; base < cnt; base += (64 << 6)) {
        const int npts = min(64, cnt - base);
        __syncthreads();                        // previous tile's reads done
        if (t < 64) {
            int idx = sel_list[b * NPT + base + min(t, npts - 1)];  // pad = dup last
            const float* xp = x + ((size_t)b * NPT + idx) * 3;
            A[t] = xp[0]; A[64 + t] = xp[1]; A[128 + t] = xp[2];
        }
        __syncthreads();
        {   // L1: 3->64
            float a0 = A[p], a1 = A[64 + p], a2 = A[128 + p];
            int ocb = wv * 4;
#pragma unroll
            for (int i = 0; i < 4; ++i) {
                int oc = ocb + i;
                float acc = b1[oc] + a0 * w1[oc*3+0] + a1 * w1[oc*3+1] + a2 * w1[oc*3+2];
                Bf[oc*64+p] = fmaxf(acc, 0.0f);
            }
        }
        __syncthreads();
        layer64(Bf, A, w2, b2, wv * 4, p);      // L2: 64->64
        __syncthreads();
        layer64(A, Bf, w3, b3, wv * 4, p);      // L3: 64->64
        __syncthreads();
        {   // L4: 64->128
            int ocb = wv * 8;
            float acc[8];
#pragma unroll
            for (int i = 0; i < 8; ++i) acc[i] = b4[ocb + i];
#pragma unroll 4
            for (int k = 0; k < 64; ++k) {
                float a = Bf[k*64+p];
#pragma unroll
                for (int i = 0; i < 8; ++i) acc[i] += a * w4[(ocb+i)*64+k];
            }
#pragma unroll
            for (int i = 0; i < 8; ++i) A[(ocb+i)*64+p] = fmaxf(acc[i], 0.0f);
        }
        __syncthreads();
        {   // L5 slice + max-pool: this block's z-quarter only (proven shape)
            int ocb = z * 256 + wv * 16;
            float acc[16];
#pragma unroll
            for (int i = 0; i < 16; ++i) acc[i] = b5[ocb + i];
#pragma unroll 4
            for (int k = 0; k < 128; ++k) {
                float a = A[k*64+p];
#pragma unroll
                for (int i = 0; i < 16; ++i) acc[i] += a * w5[(ocb+i)*128+k];
            }
#pragma unroll
            for (int i = 0; i < 16; ++i) {
                float v = (p < npts) ? fmaxf(acc[i], 0.0f) : 0.0f;  // pad -> 0 (relu>=0)
#pragma unroll
                for (int m = 1; m < 64; m <<= 1) v = fmaxf(v, __shfl_xor(v, m, 64));
                if (p == 0) atomicMax((int*)&pool[b*NCC + ocb + i], __float_as_int(v));
            }
        }
    }
}

// ---------------------------------------------------------------------------
// FC head (proven). head1: FC1 (1024->512 relu), 4 blocks/batch.
// ---------------------------------------------------------------------------
__global__ __launch_bounds__(1024) void head1_kernel(const float* __restrict__ pool,
    const float* __restrict__ fw1, const float* __restrict__ fb1,
    float* __restrict__ h1g)
{
    const int bo = blockIdx.x, b = blockIdx.y, t = threadIdx.x;
    const int lane = t & 63, w = t >> 6;
    __shared__ float g[1024];
    g[t] = pool[b*NCC + t];
    __syncthreads();
    int o = bo * 128 + w * 8;
#pragma unroll
    for (int i = 0; i < 8; ++i, ++o) {
        float acc = 0.0f;
#pragma unroll
        for (int j = 0; j < 16; ++j) {
            int k = lane + (j << 6);
            acc += g[k] * fw1[o*1024 + k];
        }
#pragma unroll
        for (int m = 1; m < 64; m <<= 1) acc += __shfl_xor(acc, m, 64);
        if (lane == 0) h1g[b*512 + o] = fmaxf(acc + fb1[o], 0.0f);
    }
}

// head2: FC2 (512->256 relu) + FC3 (256->3). One block per batch.
__global__ __launch_bounds__(1024) void head2_kernel(const float* __restrict__ h1g,
    const float* __restrict__ fw2, const float* __restrict__ fb2,
    const float* __restrict__ fw3, const float* __restrict__ fb3,
    float* __restrict__ out)
{
    const int b = blockIdx.x, t = threadIdx.x;
    const int lane = t & 63, w = t >> 6;
    __shared__ float h1[512], h2[256];
    if (t < 512) h1[t] = h1g[b*512 + t];
    __syncthreads();
#pragma unroll
    for (int i = 0; i < 16; ++i) {
        int o = w * 16 + i;
        float acc = 0.0f;
#pragma unroll
        for (int j = 0; j < 8; ++j) {
            int k = lane + (j << 6);
            acc += h1[k] * fw2[o*512 + k];
        }
#pragma unroll
        for (int m = 1; m < 64; m <<= 1) acc += __shfl_xor(acc, m, 64);
        if (lane == 0) h2[o] = fmaxf(acc + fb2[o], 0.0f);
    }
    __syncthreads();
    if (w < 3) {
        float acc = 0.0f;
#pragma unroll
        for (int j = 0; j < 4; ++j) {
            int k = lane + (j << 6);
            acc += h2[k] * fw3[w*256 + k];
        }
#pragma unroll
        for (int m = 1; m < 64; m <<= 1) acc += __shfl_xor(acc, m, 64);
        if (lane == 0) out[b*3 + w] = acc + fb3[w];
    }
}

extern "C" void kernel_launch(void* const* d_in, const int* in_sizes, int n_in,
                              void* d_out, int out_size, void* d_ws, size_t ws_size,
                              hipStream_t stream)
{
    const float* x    = (const float*)d_in[0];
    const int*   far0 = (const int*)  d_in[1];
    const float *w1 = (const float*)d_in[2],  *b1 = (const float*)d_in[3];
    const float *w2 = (const float*)d_in[4],  *b2 = (const float*)d_in[5];
    const float *w3 = (const float*)d_in[6],  *b3 = (const float*)d_in[7];
    const float *w4 = (const float*)d_in[8],  *b4 = (const float*)d_in[9];
    const float *w5 = (const float*)d_in[10], *b5 = (const float*)d_in[11];
    const float *fw1 = (const float*)d_in[12], *fb1 = (const float*)d_in[13];
    const float *fw2 = (const float*)d_in[14], *fb2 = (const float*)d_in[15];
    const float *fw3 = (const float*)d_in[16], *fb3 = (const float*)d_in[17];

    char* ws = (char*)d_ws;
    int*      ccount = (int*)     (ws + OFF_CCOUNT);
    int*      scount = (int*)     (ws + OFF_SCOUNT);
    unsigned* sbits  = (unsigned*)(ws + OFF_SBITS);
    float*    pool   = (float*)   (ws + OFF_POOL);
    int*      clist  = (int*)     (ws + OFF_CLIST);
    float*    h1g    = (float*)   (ws + OFF_H1);
    int*      slist  = (int*)     (ws + OFF_SLIST);

    hipMemsetAsync(d_ws, 0, ZERO_BYTES, stream);  // counts, sbits, pool -> 0

    fps_kernel<<<BN, 512, 0, stream>>>(x, far0, clist, ccount);
    knn_kernel<<<dim3(NCC/CCH, BN), 1024, 0, stream>>>(x, clist, ccount, sbits, slist, scount);
    mlp_kernel<<<dim3(64, BN, 4), 1024, 0, stream>>>(x, slist, scount,
        w1,b1, w2,b2, w3,b3, w4,b4, w5,b5, pool);
    head1_kernel<<<dim3(4, BN), 1024, 0, stream>>>(pool, fw1, fb1, h1g);
    head2_kernel<<<BN, 1024, 0, stream>>>(h1g, fw2,fb2, fw3,fb3, (float*)d_out);
}

// Round 6
// 193.038 us; speedup vs baseline: 1.8163x; 1.3513x over previous
//
#include <hip/hip_runtime.h>

// Problem constants (fixed by setup_inputs / reference)
#define BN  4       // batch
#define NPT 16384   // points per batch
#define NCC 1024    // FPS centroids (cap on unique orbit length)
#define KNN 32      // neighbors

// KNN select parameters
#define HBINS    2048   // 11-bit level-1 histogram
#define CCH      4      // centroids per chunk-block
#define CAND_CAP 768    // boundary-bin candidate cap (overflow -> exact drill)

// Workspace layout (bytes). Total ~305 KB.
#define OFF_CCOUNT 0                          // BN ints
#define OFF_SCOUNT 64                         // BN ints
#define OFF_SBITS  128                        // BN*(NPT/32) u32 = 8 KB
#define OFF_POOL   (128 + BN*(NPT/32)*4)      // BN*NCC floats = 16 KB
#define ZERO_BYTES (OFF_POOL + BN*NCC*4)
#define OFF_CLIST  ZERO_BYTES                 // BN*NCC ints = 16 KB
#define OFF_H1     (OFF_CLIST + BN*NCC*4)     // BN*512 floats = 8 KB
#define OFF_SLIST  (OFF_H1 + BN*512*4)        // BN*NPT ints = 256 KB

typedef short bf16x8 __attribute__((ext_vector_type(8)));
typedef float f32x4  __attribute__((ext_vector_type(4)));

__device__ __forceinline__ short f2bf(float f) {   // RNE fp32 -> bf16
    unsigned u = __float_as_uint(f);
    return (short)((u + 0x7fffu + ((u >> 16) & 1u)) >> 16);
}
__device__ __forceinline__ bf16x8 cvt8(const float* __restrict__ p) {
    bf16x8 v;
#pragma unroll
    for (int j = 0; j < 8; ++j) v[j] = f2bf(p[j]);
    return v;
}

// ---------------------------------------------------------------------------
// FPS v4: 512 threads, 32 pts/thread in regs, ONE barrier per iteration.
// 3-slot rotating packed-u64 argmax: for slot s used at iter it (s=it%3),
// atomicMax is in epoch E_it, the read in E_{it+1}, the re-zero of slot
// (it+2)%3 in E_{it+1} -- every conflicting pair is barrier-separated.
// seen[] is written only PRE-barrier (t0, for prev centroid) and read only
// POST-barrier -> no same-epoch race; break is uniform. Coords re-read from
// global via readfirstlane (s_load broadcast) instead of a 2nd barrier.
// Distance formula unchanged (__f*_rn, exact reference semantics).
// ---------------------------------------------------------------------------
__global__ __launch_bounds__(512) void fps_kernel(const float* __restrict__ x,
    const int* __restrict__ far_init, int* __restrict__ clist, int* __restrict__ ccount)
{
    const int b = blockIdx.x, t = threadIdx.x;
    __shared__ __align__(16) unsigned char seen[NPT];
    __shared__ unsigned long long slot[3];

    const float* xb = x + (size_t)b * NPT * 3;
    float px[32], py[32], pz[32];
#pragma unroll
    for (int j = 0; j < 32; ++j) {
        int idx = t + (j << 9);
        px[j] = xb[idx*3+0]; py[j] = xb[idx*3+1]; pz[j] = xb[idx*3+2];
    }
    ((uint4*)seen)[t]       = make_uint4(0,0,0,0);
    ((uint4*)seen)[t + 512] = make_uint4(0,0,0,0);
    if (t == 0) { slot[0] = 0ull; slot[1] = 0ull; slot[2] = 0ull; }
    int prev_bx = far_init[b];                    // uniform (same global read)
    __syncthreads();
    int pbs = __builtin_amdgcn_readfirstlane(prev_bx);
    float cx = xb[pbs*3], cy = xb[pbs*3+1], cz = xb[pbs*3+2];

    int done = 0;
    for (int it = 0; it < NCC-1; ++it) {
        const int p = it % 3;
        float best = -1.0f; int bi = 0;
#pragma unroll
        for (int j = 0; j < 32; ++j) {
            float dx = __fsub_rn(px[j], cx);
            float dy = __fsub_rn(py[j], cy);
            float dz = __fsub_rn(pz[j], cz);
            float d  = __fadd_rn(__fadd_rn(__fmul_rn(dx,dx), __fmul_rn(dy,dy)),
                                 __fmul_rn(dz,dz));
            int idx = t + (j << 9);               // ascending: strict > keeps first
            if (d > best) { best = d; bi = idx; }
        }
#pragma unroll
        for (int m = 1; m < 64; m <<= 1) {
            float od = __shfl_xor(best, m, 64);
            int   oi = __shfl_xor(bi,   m, 64);
            if (od > best || (od == best && oi < bi)) { best = od; bi = oi; }
        }
        if ((t & 63) == 0) {
            unsigned long long pk =
                (((unsigned long long)__float_as_uint(best)) << 32)
                | (unsigned)(NPT - 1 - bi);
            atomicMax(&slot[p], pk);
        }
        if (t == 0) seen[prev_bx] = 1;            // pre-barrier write, no readers now
        __syncthreads();                          // THE barrier
        int bx = NPT - 1 - (int)(unsigned)(slot[p] & 0xFFFFFFFFull);
        if (t == 0) slot[(it + 2) % 3] = 0ull;    // safe: barrier-separated both ways
        if (seen[bx]) { done = 1; break; }        // uniform (stable post-barrier)
        prev_bx = bx;
        int bxs = __builtin_amdgcn_readfirstlane(bx);
        cx = xb[bxs*3]; cy = xb[bxs*3+1]; cz = xb[bxs*3+2];
    }
    if (!done && t == 0) seen[prev_bx] = 1;       // full-length orbit: mark last
    __syncthreads();
    // Emit unique-centroid list (order-free; downstream is set-invariant).
#pragma unroll
    for (int j = 0; j < 32; ++j) {
        int idx = t + (j << 9);
        if (seen[idx]) {
            int pos = atomicAdd(&ccount[b], 1);
            clist[b * NCC + pos] = idx;
        }
    }
}

// ---------------------------------------------------------------------------
// KNN v3 (proven): chunk-PARALLEL, grid=(NCC/CCH, BN). Exact 32nd-smallest
// key per centroid, union-mark + compacted list via bitmask dedupe.
// ---------------------------------------------------------------------------
__device__ __forceinline__ unsigned key_of(float px, float py, float pz, float xn,
                                           float cx, float cy, float cz, float cn)
{
    float dot = __fadd_rn(__fadd_rn(__fmul_rn(cx,px), __fmul_rn(cy,py)), __fmul_rn(cz,pz));
    float d2  = __fsub_rn(__fadd_rn(cn, xn), __fmul_rn(2.0f, dot));
    unsigned u = __float_as_uint(d2);
    return u ^ ((u >> 31) ? 0xFFFFFFFFu : 0x80000000u);
}

__device__ __forceinline__ void wave_scan_bins(const unsigned* __restrict__ H,
    int nbins, int rem, int lane, int* __restrict__ out_bin, int* __restrict__ out_below)
{
    int per = nbins >> 6;
    int base = lane * per;
    unsigned part = 0;
    for (int q = 0; q < per; ++q) part += H[base + q];
    unsigned inc = part;
#pragma unroll
    for (int m = 1; m < 64; m <<= 1) {
        unsigned u = __shfl_up(inc, m, 64);
        if (lane >= m) inc += u;
    }
    unsigned exc = inc - part;
    unsigned long long mk = __ballot(exc < (unsigned)rem && inc >= (unsigned)rem);
    int src = __ffsll((long long)mk) - 1;
    if (lane == src) {
        unsigned run = exc; int bb = base;
        for (int q = 0; q < per; ++q) {
            unsigned h = H[base + q];
            if (run + h >= (unsigned)rem) { bb = base + q; break; }
            run += h;
        }
        *out_bin = bb; *out_below = (int)run;
    }
}

__global__ __launch_bounds__(1024) void knn_kernel(const float* __restrict__ x,
    const int* __restrict__ clist, const int* __restrict__ ccount,
    unsigned* __restrict__ sbits, int* __restrict__ slist, int* __restrict__ scount)
{
    const int b = blockIdx.y, t = threadIdx.x;
    const int lane = t & 63, w = t >> 6;
    const int cnt = ccount[b];
    const int cbase = blockIdx.x * CCH;
    if (cbase >= cnt) return;                  // uniform exit, before any barrier
    const int nc = min(CCH, cnt - cbase);
    const float* xb = x + (size_t)b * NPT * 3;

    __shared__ unsigned hist[CCH * HBINS];     // 32 KB
    __shared__ unsigned cand[CCH * CAND_CAP];  // 12 KB
    __shared__ float cpx[CCH], cpy[CCH], cpz[CCH], cpn[CCH];
    __shared__ unsigned candCnt[CCH];
    __shared__ int s_bb[CCH], s_below[CCH], s_rrem[CCH], s_need[CCH], s_pref[CCH];
    __shared__ unsigned s_tau[CCH];
    __shared__ int s_tbin, s_tbelow;

    if (t < nc) {
        int ci = clist[b * NCC + cbase + t];
        float cx = xb[ci*3], cy = xb[ci*3+1], cz = xb[ci*3+2];
        cpx[t] = cx; cpy[t] = cy; cpz[t] = cz;
        cpn[t] = __fadd_rn(__fadd_rn(__fmul_rn(cx,cx), __fmul_rn(cy,cy)), __fmul_rn(cz,cz));
        candCnt[t] = 0;
    }
    for (int i = t; i < CCH * HBINS; i += 1024) hist[i] = 0;
    __syncthreads();

    for (int j = 0; j < NPT/1024; ++j) {
        int i = t + (j << 10);
        float px = xb[i*3], py = xb[i*3+1], pz = xb[i*3+2];
        float xn = __fadd_rn(__fadd_rn(__fmul_rn(px,px), __fmul_rn(py,py)), __fmul_rn(pz,pz));
#pragma unroll
        for (int c = 0; c < CCH; ++c) {
            if (c < nc) {
                unsigned key = key_of(px,py,pz,xn, cpx[c],cpy[c],cpz[c],cpn[c]);
                atomicAdd(&hist[c*HBINS + (key >> 21)], 1u);
            }
        }
    }
    __syncthreads();

    if (w < nc)
        wave_scan_bins(&hist[w*HBINS], HBINS, KNN, lane, &s_bb[w], &s_below[w]);
    __syncthreads();
    if (t < nc) s_rrem[t] = KNN - s_below[t];
    __syncthreads();

    for (int j = 0; j < NPT/1024; ++j) {
        int i = t + (j << 10);
        float px = xb[i*3], py = xb[i*3+1], pz = xb[i*3+2];
        float xn = __fadd_rn(__fadd_rn(__fmul_rn(px,px), __fmul_rn(py,py)), __fmul_rn(pz,pz));
#pragma unroll
        for (int c = 0; c < CCH; ++c) {
            if (c < nc) {
                unsigned key = key_of(px,py,pz,xn, cpx[c],cpy[c],cpz[c],cpn[c]);
                if ((int)(key >> 21) == s_bb[c]) {
                    unsigned pos = atomicAdd(&candCnt[c], 1u);
                    if (pos < CAND_CAP) cand[c*CAND_CAP + pos] = key;
                }
            }
        }
    }
    __syncthreads();

    if (w < nc) {
        unsigned cc = candCnt[w];
        if (cc <= CAND_CAP) {
            int r = s_rrem[w] - 1;
            const unsigned* C = &cand[w*CAND_CAP];
            for (int idx = lane; idx < (int)cc; idx += 64) {
                unsigned k = C[idx]; int rank = 0;
                for (int q = 0; q < (int)cc; ++q) {
                    unsigned kq = C[q];
                    rank += (kq < k || (kq == k && q < idx)) ? 1 : 0;
                }
                if (rank == r) s_tau[w] = k;
            }
            if (lane == 0) s_need[w] = 0;
        } else if (lane == 0) s_need[w] = 1;
    }
    __syncthreads();

    for (int c = 0; c < nc; ++c) {
        if (s_need[c]) {
            const float cx = cpx[c], cy = cpy[c], cz = cpz[c], cn = cpn[c];
            for (int i = t; i < HBINS; i += 1024) hist[i] = 0;
            __syncthreads();
            for (int j = 0; j < NPT/1024; ++j) {
                int i = t + (j << 10);
                float px = xb[i*3], py = xb[i*3+1], pz = xb[i*3+2];
                float xn = __fadd_rn(__fadd_rn(__fmul_rn(px,px), __fmul_rn(py,py)), __fmul_rn(pz,pz));
                unsigned key = key_of(px,py,pz,xn, cx,cy,cz,cn);
                if ((int)(key >> 21) == s_bb[c]) atomicAdd(&hist[(key >> 10) & 2047u], 1u);
            }
            __syncthreads();
            if (w == 0) wave_scan_bins(hist, HBINS, s_rrem[c], lane, &s_tbin, &s_tbelow);
            __syncthreads();
            if (t == 0) { s_pref[c] = (s_bb[c] << 11) | s_tbin; s_rrem[c] -= s_tbelow; }
            __syncthreads();
            for (int i = t; i < 1024; i += 1024) hist[i] = 0;
            __syncthreads();
            for (int j = 0; j < NPT/1024; ++j) {
                int i = t + (j << 10);
                float px = xb[i*3], py = xb[i*3+1], pz = xb[i*3+2];
                float xn = __fadd_rn(__fadd_rn(__fmul_rn(px,px), __fmul_rn(py,py)), __fmul_rn(pz,pz));
                unsigned key = key_of(px,py,pz,xn, cx,cy,cz,cn);
                if ((int)(key >> 10) == s_pref[c]) atomicAdd(&hist[key & 1023u], 1u);
            }
            __syncthreads();
            if (w == 0) wave_scan_bins(hist, 1024, s_rrem[c], lane, &s_tbin, &s_tbelow);
            __syncthreads();
            if (t == 0) s_tau[c] = (((unsigned)s_pref[c]) << 10) | (unsigned)s_tbin;
            __syncthreads();
        }
    }
    __syncthreads();

    for (int j = 0; j < NPT/1024; ++j) {
        int i = t + (j << 10);
        float px = xb[i*3], py = xb[i*3+1], pz = xb[i*3+2];
        float xn = __fadd_rn(__fadd_rn(__fmul_rn(px,px), __fmul_rn(py,py)), __fmul_rn(pz,pz));
        bool sel = false;
#pragma unroll
        for (int c = 0; c < CCH; ++c) {
            if (c < nc) {
                unsigned key = key_of(px,py,pz,xn, cpx[c],cpy[c],cpz[c],cpn[c]);
                sel |= (key <= s_tau[c]);
            }
        }
        if (sel) {
            unsigned bit = 1u << (i & 31);
            unsigned old = atomicOr(&sbits[b*(NPT/32) + (i >> 5)], bit);
            if (!(old & bit)) {
                int pos = atomicAdd(&scount[b], 1);
                slist[b * NPT + pos] = i;
            }
        }
    }
}

// ---------------------------------------------------------------------------
// MLP v4: MFMA (16x16x32 bf16), weights persistent in VGPR B-frags across the
// whole tile loop -> zero per-tile weight refetch (the R3/R5 stall source).
// Layouts (m89/m120 HW-verified): A[m=lane&15][k=quad*8+j],
// B[k][n=lane&15], D[row=quad*4+reg][col=lane&15]. Acts bf16 in LDS, padded
// strides (72/136 elems) for <=2-way banks. L1 (k=3) stays fp32 VALU.
// grid=(32, BN, 4): z = 256-oc slice of L5; pad pts duplicate-last (max-safe).
// ---------------------------------------------------------------------------
#define MFMA16(a, bfr, c) __builtin_amdgcn_mfma_f32_16x16x32_bf16(a, bfr, c, 0, 0, 0)

__global__ __launch_bounds__(1024) void mlp_kernel(const float* __restrict__ x,
    const int* __restrict__ sel_list, const int* __restrict__ sel_count,
    const float* __restrict__ w1, const float* __restrict__ b1,
    const float* __restrict__ w2, const float* __restrict__ b2,
    const float* __restrict__ w3, const float* __restrict__ b3,
    const float* __restrict__ w4, const float* __restrict__ b4,
    const float* __restrict__ w5, const float* __restrict__ b5,
    float* __restrict__ pool)
{
    const int b = blockIdx.y, z = blockIdx.z, t = threadIdx.x;
    const int cnt = sel_count[b];
    if ((blockIdx.x << 6) >= cnt) return;      // uniform, before any barrier
    const int lane = t & 63;
    const int w    = __builtin_amdgcn_readfirstlane(t >> 6);  // 0..15
    const int m    = lane & 15, quad = lane >> 4;

    __shared__ __align__(16) short A1[64 * 72];    // 9 KB
    __shared__ __align__(16) short A2[64 * 72];    // 9 KB
    __shared__ __align__(16) short A3[64 * 136];   // 17 KB
    __shared__ float sx[3 * 64];

    // ---- persistent weight fragments (once per block) ----
    const int ocA = (w >> 2) * 16 + m;             // L2/L3 oc (wave>>2 = oc_tile)
    bf16x8 bw2[2], bw3[2], bw4[2][2], bw5[4];
#pragma unroll
    for (int ks = 0; ks < 2; ++ks) {
        bw2[ks] = cvt8(w2 + ocA*64 + ks*32 + quad*8);
        bw3[ks] = cvt8(w3 + ocA*64 + ks*32 + quad*8);
    }
    int oc4i[2];
#pragma unroll
    for (int r2 = 0; r2 < 2; ++r2) {
        oc4i[r2] = ((w >> 2) + 4*r2) * 16 + m;
#pragma unroll
        for (int ks = 0; ks < 2; ++ks)
            bw4[r2][ks] = cvt8(w4 + oc4i[r2]*64 + ks*32 + quad*8);
    }
    const int oc5 = z*256 + w*16 + m;
#pragma unroll
    for (int ks = 0; ks < 4; ++ks)
        bw5[ks] = cvt8(w5 + oc5*128 + ks*32 + quad*8);
    const float bias2 = b2[ocA], bias3 = b3[ocA];
    const float bias4_0 = b4[oc4i[0]], bias4_1 = b4[oc4i[1]];
    const float bias5 = b5[oc5];
    float w1v[4][3], b1v[4];
#pragma unroll
    for (int i = 0; i < 4; ++i) {
        int oc = w*4 + i;
        w1v[i][0] = w1[oc*3+0]; w1v[i][1] = w1[oc*3+1]; w1v[i][2] = w1[oc*3+2];
        b1v[i] = b1[oc];
    }
    const int pt0 = (w & 3) * 16;                  // pt tile for L2/L3/L4

    for (int base = blockIdx.x << 6; base < cnt; base += (32 << 6)) {
        const int npts = min(64, cnt - base);
        __syncthreads();                            // prev tile fully consumed
        if (t < 64) {
            int idx = sel_list[b * NPT + base + min(t, npts - 1)];  // pad = dup last
            const float* xp = x + ((size_t)b * NPT + idx) * 3;
            sx[t] = xp[0]; sx[64 + t] = xp[1]; sx[128 + t] = xp[2];
        }
        __syncthreads();
        {   // L1: 3->64, fp32 VALU, write bf16 [pt][72]
            float x0 = sx[lane], x1 = sx[64 + lane], x2 = sx[128 + lane];
#pragma unroll
            for (int i = 0; i < 4; ++i) {
                float acc = fmaf(x2, w1v[i][2], fmaf(x1, w1v[i][1],
                             fmaf(x0, w1v[i][0], b1v[i])));
                A1[lane*72 + w*4 + i] = f2bf(fmaxf(acc, 0.0f));
            }
        }
        __syncthreads();
        {   // L2: A1 -> A2 (64->64)
            bf16x8 a0 = *(const bf16x8*)&A1[(pt0 + m)*72 + quad*8];
            bf16x8 a1 = *(const bf16x8*)&A1[(pt0 + m)*72 + 32 + quad*8];
            f32x4 d = {0.f, 0.f, 0.f, 0.f};
            d = MFMA16(a0, bw2[0], d);
            d = MFMA16(a1, bw2[1], d);
#pragma unroll
            for (int r = 0; r < 4; ++r)
                A2[(pt0 + quad*4 + r)*72 + ocA] = f2bf(fmaxf(d[r] + bias2, 0.0f));
        }
        __syncthreads();
        {   // L3: A2 -> A1 (64->64)
            bf16x8 a0 = *(const bf16x8*)&A2[(pt0 + m)*72 + quad*8];
            bf16x8 a1 = *(const bf16x8*)&A2[(pt0 + m)*72 + 32 + quad*8];
            f32x4 d = {0.f, 0.f, 0.f, 0.f};
            d = MFMA16(a0, bw3[0], d);
            d = MFMA16(a1, bw3[1], d);
#pragma unroll
            for (int r = 0; r < 4; ++r)
                A1[(pt0 + quad*4 + r)*72 + ocA] = f2bf(fmaxf(d[r] + bias3, 0.0f));
        }
        __syncthreads();
        {   // L4: A1 -> A3 (64->128), 2 oc-tiles per wave
            bf16x8 a0 = *(const bf16x8*)&A1[(pt0 + m)*72 + quad*8];
            bf16x8 a1 = *(const bf16x8*)&A1[(pt0 + m)*72 + 32 + quad*8];
#pragma unroll
            for (int r2 = 0; r2 < 2; ++r2) {
                f32x4 d = {0.f, 0.f, 0.f, 0.f};
                d = MFMA16(a0, bw4[r2][0], d);
                d = MFMA16(a1, bw4[r2][1], d);
                float bs = r2 ? bias4_1 : bias4_0;
#pragma unroll
                for (int r = 0; r < 4; ++r)
                    A3[(pt0 + quad*4 + r)*136 + oc4i[r2]] = f2bf(fmaxf(d[r] + bs, 0.0f));
            }
        }
        __syncthreads();
        {   // L5 (128 -> this block's 256-oc slice) + max-pool
            float vm = 0.0f;                        // relu outputs >= 0
#pragma unroll
            for (int pt4 = 0; pt4 < 4; ++pt4) {
                const int q0 = pt4 * 16;
                f32x4 d = {0.f, 0.f, 0.f, 0.f};
#pragma unroll
                for (int ks = 0; ks < 4; ++ks) {
                    bf16x8 a = *(const bf16x8*)&A3[(q0 + m)*136 + ks*32 + quad*8];
                    d = MFMA16(a, bw5[ks], d);
                }
#pragma unroll
                for (int r = 0; r < 4; ++r)
                    vm = fmaxf(vm, fmaxf(d[r] + bias5, 0.0f));
            }
            vm = fmaxf(vm, __shfl_xor(vm, 16, 64));
            vm = fmaxf(vm, __shfl_xor(vm, 32, 64));
            if (lane < 16)
                atomicMax((int*)&pool[b*NCC + z*256 + w*16 + lane], __float_as_int(vm));
        }
    }
}

// ---------------------------------------------------------------------------
// FC head (proven, fp32 exact). head1: FC1 (1024->512 relu), 4 blocks/batch.
// ---------------------------------------------------------------------------
__global__ __launch_bounds__(1024) void head1_kernel(const float* __restrict__ pool,
    const float* __restrict__ fw1, const float* __restrict__ fb1,
    float* __restrict__ h1g)
{
    const int bo = blockIdx.x, b = blockIdx.y, t = threadIdx.x;
    const int lane = t & 63, w = t >> 6;
    __shared__ float g[1024];
    g[t] = pool[b*NCC + t];
    __syncthreads();
    int o = bo * 128 + w * 8;
#pragma unroll
    for (int i = 0; i < 8; ++i, ++o) {
        float acc = 0.0f;
#pragma unroll
        for (int j = 0; j < 16; ++j) {
            int k = lane + (j << 6);
            acc += g[k] * fw1[o*1024 + k];
        }
#pragma unroll
        for (int m = 1; m < 64; m <<= 1) acc += __shfl_xor(acc, m, 64);
        if (lane == 0) h1g[b*512 + o] = fmaxf(acc + fb1[o], 0.0f);
    }
}

// head2: FC2 (512->256 relu) + FC3 (256->3). One block per batch.
__global__ __launch_bounds__(1024) void head2_kernel(const float* __restrict__ h1g,
    const float* __restrict__ fw2, const float* __restrict__ fb2,
    const float* __restrict__ fw3, const float* __restrict__ fb3,
    float* __restrict__ out)
{
    const int b = blockIdx.x, t = threadIdx.x;
    const int lane = t & 63, w = t >> 6;
    __shared__ float h1[512], h2[256];
    if (t < 512) h1[t] = h1g[b*512 + t];
    __syncthreads();
#pragma unroll
    for (int i = 0; i < 16; ++i) {
        int o = w * 16 + i;
        float acc = 0.0f;
#pragma unroll
        for (int j = 0; j < 8; ++j) {
            int k = lane + (j << 6);
            acc += h1[k] * fw2[o*512 + k];
        }
#pragma unroll
        for (int m = 1; m < 64; m <<= 1) acc += __shfl_xor(acc, m, 64);
        if (lane == 0) h2[o] = fmaxf(acc + fb2[o], 0.0f);
    }
    __syncthreads();
    if (w < 3) {
        float acc = 0.0f;
#pragma unroll
        for (int j = 0; j < 4; ++j) {
            int k = lane + (j << 6);
            acc += h2[k] * fw3[w*256 + k];
        }
#pragma unroll
        for (int m = 1; m < 64; m <<= 1) acc += __shfl_xor(acc, m, 64);
        if (lane == 0) out[b*3 + w] = acc + fb3[w];
    }
}

extern "C" void kernel_launch(void* const* d_in, const int* in_sizes, int n_in,
                              void* d_out, int out_size, void* d_ws, size_t ws_size,
                              hipStream_t stream)
{
    const float* x    = (const float*)d_in[0];
    const int*   far0 = (const int*)  d_in[1];
    const float *w1 = (const float*)d_in[2],  *b1 = (const float*)d_in[3];
    const float *w2 = (const float*)d_in[4],  *b2 = (const float*)d_in[5];
    const float *w3 = (const float*)d_in[6],  *b3 = (const float*)d_in[7];
    const float *w4 = (const float*)d_in[8],  *b4 = (const float*)d_in[9];
    const float *w5 = (const float*)d_in[10], *b5 = (const float*)d_in[11];
    const float *fw1 = (const float*)d_in[12], *fb1 = (const float*)d_in[13];
    const float *fw2 = (const float*)d_in[14], *fb2 = (const float*)d_in[15];
    const float *fw3 = (const float*)d_in[16], *fb3 = (const float*)d_in[17];

    char* ws = (char*)d_ws;
    int*      ccount = (int*)     (ws + OFF_CCOUNT);
    int*      scount = (int*)     (ws + OFF_SCOUNT);
    unsigned* sbits  = (unsigned*)(ws + OFF_SBITS);
    float*    pool   = (float*)   (ws + OFF_POOL);
    int*      clist  = (int*)     (ws + OFF_CLIST);
    float*    h1g    = (float*)   (ws + OFF_H1);
    int*      slist  = (int*)     (ws + OFF_SLIST);

    hipMemsetAsync(d_ws, 0, ZERO_BYTES, stream);  // counts, sbits, pool -> 0

    fps_kernel<<<BN, 512, 0, stream>>>(x, far0, clist, ccount);
    knn_kernel<<<dim3(NCC/CCH, BN), 1024, 0, stream>>>(x, clist, ccount, sbits, slist, scount);
    mlp_kernel<<<dim3(32, BN, 4), 1024, 0, stream>>>(x, slist, scount,
        w1,b1, w2,b2, w3,b3, w4,b4, w5,b5, pool);
    head1_kernel<<<dim3(4, BN), 1024, 0, stream>>>(pool, fw1, fb1, h1g);
    head2_kernel<<<BN, 1024, 0, stream>>>(h1g, fw2,fb2, fw3,fb3, (float*)d_out);
}